// Round 18
// baseline (1639.733 us; speedup 1.0000x reference)
//
#include <hip/hip_runtime.h>
#include <math.h>

typedef unsigned short ushort_t;
typedef unsigned int uint_t;
typedef __attribute__((ext_vector_type(8))) short short8;
typedef __attribute__((ext_vector_type(4))) float f32x4;

// ---------------- problem constants ----------------
constexpr int Bb = 4, Ss = 1024, Dd = 1024, Nn = 64, Hh = 16;
constexpr int DIi = 2048, DFf = 4096;
constexpr int TOKENS = Bb * Ss;          // 4096

// per-layer bf16 weight arena segment offsets (in elements)
constexpr size_t O_IN  = 0;                         // 4096x1024
constexpr size_t O_DT  = 4194304;                   // 1152x2048 (W_dt ++ W_xp padded)
constexpr size_t O_XP  = O_DT + 2097152;            // (xp rows live here)
constexpr size_t O_OUT = O_XP + 262144;             // 1024x2048
constexpr size_t O_QKV = O_OUT + 2097152;           // 3072x1024
constexpr size_t O_AO  = O_QKV + 3145728;           // 1024x1024
constexpr size_t O_F1  = O_AO + 1048576;            // 4096x1024
constexpr size_t O_F2  = O_F1 + 4194304;            // 1024x4096
constexpr size_t W_TOTAL = O_F2 + 4194304;          // 21,233,664
constexpr size_t W_QUADS = W_TOTAL / 4;             // 5,308,416

enum { EPI_SPLIT = 0, EPI_QKV, EPI_GELU, EPI_DTXP, EPI_DP, EPI_F32, EPI_RESID };

__device__ __forceinline__ float siluf(float x) { return x / (1.f + expf(-x)); }
__device__ __forceinline__ float softplusf(float x) { return fmaxf(x, 0.f) + log1pf(expf(-fabsf(x))); }
__device__ __forceinline__ float geluf(float x) { return 0.5f * x * (1.f + erff(x * 0.7071067811865476f)); }

__device__ __forceinline__ float bf2f(uint_t u) {
    union { uint_t i; float f; } v; v.i = u << 16; return v.f;
}
__device__ __forceinline__ ushort_t f2bf(float f) {   // RNE
    union { float f; uint_t i; } v; v.f = f;
    return (ushort_t)((v.i + 0x7FFFu + ((v.i >> 16) & 1u)) >> 16);
}

__device__ __forceinline__ void gload_lds16(const ushort_t* g, ushort_t* l) {
    __builtin_amdgcn_global_load_lds(
        (const __attribute__((address_space(1))) unsigned int*)g,
        (__attribute__((address_space(3))) unsigned int*)l, 16, 0, 0);
}

__device__ __forceinline__ void wait_vm(int n) {
    if (n == 0)      asm volatile("s_waitcnt vmcnt(0)" ::: "memory");
    else if (n == 4) asm volatile("s_waitcnt vmcnt(4)" ::: "memory");
    else if (n == 8) asm volatile("s_waitcnt vmcnt(8)" ::: "memory");
    else             asm volatile("s_waitcnt vmcnt(0)" ::: "memory");
}

// ---------------------------------------------------------------
// 256x256-tile bf16 GEMM for SPLIT/GELU. Round 18: T4 counted-vmcnt
// half-K pipeline. 4 buffers x 32KB (A 256x32 + B 256x32), half-step:
// issue STAGE(h+2) -> 12 ds_read + 32 MFMA on buf[h&3] -> vmcnt(4)
// (h+1 landed, h+2 in flight ACROSS the barrier) -> s_barrier.
// Loads get ~2 compute phases to land; vmcnt never drains to 0 in
// steady state (catalog T4: counted-vs-drain0 = +38%).
// Staging/read = round-8-validated [row][32] layout + (row>>1)&3
// XOR involution (identical lane arithmetic to narrow BK=32).
// ---------------------------------------------------------------
template <int EPI>
__global__ __launch_bounds__(512, 2) void gemm_wide256(
    const ushort_t* __restrict__ A, const ushort_t* __restrict__ Bw,
    const float* __restrict__ bias, int M, int N, int K,
    ushort_t* __restrict__ ob0, ushort_t* __restrict__ ob1)
{
    constexpr int BUFSZ = 16384;    // ushorts: A 256x32 (8192) | B 256x32 (8192)
    __shared__ __attribute__((aligned(16))) ushort_t AB[4 * BUFSZ];   // 128KB
    const int tid = threadIdx.x;
    const int lane = tid & 63, wid = tid >> 6;
    const int wr = wid >> 2, wc = wid & 3;
    const int l15 = lane & 15, lg = lane >> 4;

    // 2-level XCD tiling (XBY=4, XBX=2): gy=16, gx=16 -> bijective.
    int bx = blockIdx.x, by = blockIdx.y;
    const int gx = gridDim.x, gy = gridDim.y;
    if ((gy & 3) == 0 && (gx & 1) == 0) {
        const int s = by * gx + bx;
        const int xcd = s & 7, c = s >> 3;
        const int gyc = gy >> 2, gxc = gx >> 1;
        by = (xcd & 3) * gyc + (c % gyc);
        bx = (xcd >> 2) * gxc + (c / gyc);
    }
    const int m0 = by << 8, n0 = bx << 8;

    f32x4 acc[8][4];
#pragma unroll
    for (int i = 0; i < 8; ++i)
#pragma unroll
        for (int j = 0; j < 4; ++j) { acc[i][j][0]=0.f; acc[i][j][1]=0.f; acc[i][j][2]=0.f; acc[i][j][3]=0.f; }

    // staging: lane -> row (lane>>2), chunk (lane&3);
    // source chunk pre-XOR'd with (row>>1)&3 = (lane>>3)&3 (round-8 key).
    const int srow4 = lane >> 2;
    const int scc4  = (lane & 3) ^ ((lane >> 3) & 3);
    const ushort_t* Ag = A + (size_t)(m0 + wid * 32 + srow4) * K + scc4 * 8;
    const ushort_t* Bg = Bw + (size_t)(n0 + wid * 32 + srow4) * K + scc4 * 8;

    // per half-step: 4 gloads/wave (A rows wid*32+{0,16}, B same)
    auto STAGE = [&](int b_, int k0_) {
        ushort_t* d_ = AB + b_ * BUFSZ;
        gload_lds16(Ag + k0_,                  d_ + (wid * 32) * 32);
        gload_lds16(Ag + (size_t)16 * K + k0_, d_ + (wid * 32 + 16) * 32);
        gload_lds16(Bg + k0_,                  d_ + 8192 + (wid * 32) * 32);
        gload_lds16(Bg + (size_t)16 * K + k0_, d_ + 8192 + (wid * 32 + 16) * 32);
    };

    const int NS2 = K >> 5;        // half-steps of K=32
    STAGE(0, 0);
    STAGE(1, 32);
    wait_vm(4);                    // step0 landed; step1 in flight
    __builtin_amdgcn_s_barrier();

    const int chAB = (lg ^ ((l15 >> 1) & 3)) * 8;   // loop-invariant read swizzle
    for (int h = 0; h < NS2; ++h) {
        if (h + 2 < NS2) STAGE((h + 2) & 3, (h + 2) << 5);
        const ushort_t* As_ = AB + (h & 3) * BUFSZ;
        const ushort_t* Bs_ = As_ + 8192;
        short8 af[8], bfr[4];
#pragma unroll
        for (int mi = 0; mi < 8; ++mi)
            af[mi] = *(const short8*)&As_[(wr * 128 + mi * 16 + l15) * 32 + chAB];
#pragma unroll
        for (int nj = 0; nj < 4; ++nj)
            bfr[nj] = *(const short8*)&Bs_[(wc * 64 + nj * 16 + l15) * 32 + chAB];
#pragma unroll
        for (int mi = 0; mi < 8; ++mi)
#pragma unroll
            for (int nj = 0; nj < 4; ++nj)
                acc[mi][nj] = __builtin_amdgcn_mfma_f32_16x16x32_bf16(
                    af[mi], bfr[nj], acc[mi][nj], 0, 0, 0);
        if (h + 1 < NS2) {
            wait_vm((h + 2 < NS2) ? 4 : 0);
            __builtin_amdgcn_s_barrier();
        }
    }
    __syncthreads();

    // ---- epilogue: C [256][256] bf16 = 128KB, single pass ----
    const bool lo = (EPI != EPI_SPLIT) || (n0 < DIi);
#pragma unroll
    for (int nj = 0; nj < 4; ++nj) {
        const int coll = wc * 64 + nj * 16 + l15;
        const float bv = bias[n0 + coll];
#pragma unroll
        for (int mi = 0; mi < 8; ++mi)
#pragma unroll
            for (int r = 0; r < 4; ++r) {
                float v = acc[mi][nj][r] + bv;
                if (EPI == EPI_SPLIT) v = lo ? siluf(v) : v;
                else v = geluf(v);
                AB[(wr * 128 + mi * 16 + lg * 4 + r) * 256 + coll] = f2bf(v);
            }
    }
    __syncthreads();
    ushort_t* dst = (EPI == EPI_SPLIT) ? (lo ? ob0 : ob1) : ob0;
    const int Nd = (EPI == EPI_SPLIT) ? DIi : N;
    const int nb = (EPI == EPI_SPLIT && !lo) ? (n0 - DIi) : n0;
#pragma unroll
    for (int it = 0; it < 16; ++it) {
        const int c = it * 512 + tid;
        const int row = c >> 5, ch = c & 31;
        *(uint4*)&dst[(size_t)(m0 + row) * Nd + nb + ch * 8] =
            *(const uint4*)&AB[row * 256 + ch * 8];
    }
}

// ---------------------------------------------------------------
// 64x128-tile BK=64 bf16 GEMM for the narrow (N<=1152) GEMMs
// (validated round 17: +90us).
// ---------------------------------------------------------------
template <int EPI, int XBY>
__global__ __launch_bounds__(256) void gemm_narrow64(
    const ushort_t* __restrict__ A, const ushort_t* __restrict__ Bw,
    const float* __restrict__ bias, int M, int N, int K,
    float* __restrict__ of0, float* __restrict__ of1,
    ushort_t* __restrict__ ob0,
    const float* __restrict__ e0, const float* __restrict__ e1)
{
    constexpr int BUFSZ = 12288;     // A 64x64 (4096) + B 128x64 (8192) ushorts
    __shared__ __attribute__((aligned(16))) ushort_t AB[2 * BUFSZ];   // 48KB

    const int tid = threadIdx.x;
    const int lane = tid & 63, wid = tid >> 6;
    const int wc = wid;
    const int l15 = lane & 15, lg = lane >> 4;
    constexpr int XBX = 8 / XBY;

    int bx = blockIdx.x, by = blockIdx.y;
    const int gx = gridDim.x, gy = gridDim.y;
    if ((gy % XBY) == 0 && (gx % XBX) == 0) {
        const int s = by * gx + bx;
        const int xcd = s & 7, c = s >> 3;
        const int gyc = gy / XBY, gxc = gx / XBX;
        by = (xcd % XBY) * gyc + (c % gyc);
        bx = (xcd / XBY) * gxc + (c / gyc);
    }
    const int m0 = by * 64, n0 = bx << 7;

    f32x4 acc[4][2];
#pragma unroll
    for (int i = 0; i < 4; ++i)
#pragma unroll
        for (int j = 0; j < 2; ++j) { acc[i][j][0]=0.f; acc[i][j][1]=0.f; acc[i][j][2]=0.f; acc[i][j][3]=0.f; }

    const int srow8 = lane >> 3;
    const int scc8  = (lane & 7) ^ srow8;
    const ushort_t* sb[6];
    int dofs[6];
#pragma unroll
    for (int j = 0; j < 6; ++j) {
        const int i = wid * 6 + j;
        const bool isA = i < 8;
        const int rb = (isA ? i : i - 8) * 8;
        sb[j] = (isA ? A + (size_t)(m0 + rb + srow8) * K
                     : Bw + (size_t)(n0 + rb + srow8) * K) + scc8 * 8;
        dofs[j] = (isA ? 0 : 4096) + rb * 64;
    }

    auto STAGE = [&](int b_, int k0_) {
        ushort_t* d_ = AB + b_ * BUFSZ;
#pragma unroll
        for (int j = 0; j < 6; ++j)
            gload_lds16(sb[j] + k0_, d_ + dofs[j]);
    };

    const int NS = K >> 6;
    STAGE(0, 0);
    wait_vm(0);
    __builtin_amdgcn_s_barrier();
    int cur = 0;
    for (int s = 0; s < NS; ++s) {
        if (s + 1 < NS) STAGE(cur ^ 1, (s + 1) << 6);
        const ushort_t* As_ = AB + cur * BUFSZ;
        const ushort_t* Bs_ = As_ + 4096;
#pragma unroll
        for (int kk = 0; kk < 2; ++kk) {
            short8 af[4], bfr[2];
#pragma unroll
            for (int mi = 0; mi < 4; ++mi) {
                const int row = mi * 16 + l15;
                const int ch = (kk * 4 + lg) ^ (row & 7);
                af[mi] = *(const short8*)&As_[row * 64 + ch * 8];
            }
#pragma unroll
            for (int nj = 0; nj < 2; ++nj) {
                const int row = wc * 32 + nj * 16 + l15;
                const int ch = (kk * 4 + lg) ^ (row & 7);
                bfr[nj] = *(const short8*)&Bs_[row * 64 + ch * 8];
            }
#pragma unroll
            for (int mi = 0; mi < 4; ++mi)
#pragma unroll
                for (int nj = 0; nj < 2; ++nj)
                    acc[mi][nj] = __builtin_amdgcn_mfma_f32_16x16x32_bf16(
                        af[mi], bfr[nj], acc[mi][nj], 0, 0, 0);
        }
        if (s + 1 < NS) {
            wait_vm(0);
            __builtin_amdgcn_s_barrier();
        }
        cur ^= 1;
    }
    __syncthreads();

    // ---- epilogue: C 64x128 f32 = 32KB in AB; single pass ----
    float* Cf = (float*)AB;
#pragma unroll
    for (int nj = 0; nj < 2; ++nj) {
        const int coll = wc * 32 + nj * 16 + l15;
        const float bv = bias[n0 + coll];
#pragma unroll
        for (int mi = 0; mi < 4; ++mi)
#pragma unroll
            for (int r = 0; r < 4; ++r)
                Cf[(mi * 16 + lg * 4 + r) * 128 + coll] = acc[mi][nj][r] + bv;
    }
    __syncthreads();
#pragma unroll
    for (int i = 0; i < 8; ++i) {
        const int c = i * 256 + tid;
        const int row = c >> 5, ch = c & 31;
        const int grow = m0 + row;
        const int gcol = n0 + ch * 4;
        float4 v = *(const float4*)&Cf[row * 128 + ch * 4];
        if (EPI == EPI_DTXP) {
            if (n0 < Dd) {
                float ps = softplusf(v.x) + softplusf(v.y) + softplusf(v.z) + softplusf(v.w);
#pragma unroll
                for (int off = 1; off < 32; off <<= 1) ps += __shfl_xor(ps, off);
                if ((lane & 31) == 0)
                    of0[(size_t)grow * 8 + (n0 >> 7)] = ps;
            } else {
                *(float4*)&of1[(size_t)grow * 128 + (gcol - Dd)] = v;
            }
        } else if (EPI == EPI_DP) {
            const float4 e = *(const float4*)&e0[(size_t)grow * N + gcol];
            const float4 d = *(const float4*)&e1[gcol];
            v.x = fmaf(e.x, d.x, v.x); v.y = fmaf(e.y, d.y, v.y);
            v.z = fmaf(e.z, d.z, v.z); v.w = fmaf(e.w, d.w, v.w);
            *(float4*)&of0[(size_t)grow * N + gcol] = v;
        } else if (EPI == EPI_F32) {
            *(float4*)&of0[(size_t)grow * N + gcol] = v;
        } else {              // EPI_RESID: +e0 -> of0 (f32) and ob0 (bf16)
            const float4 e = *(const float4*)&e0[(size_t)grow * N + gcol];
            v.x += e.x; v.y += e.y; v.z += e.z; v.w += e.w;
            *(float4*)&of0[(size_t)grow * N + gcol] = v;
            uint2 w;
            w.x = (uint_t)f2bf(v.x) | ((uint_t)f2bf(v.y) << 16);
            w.y = (uint_t)f2bf(v.z) | ((uint_t)f2bf(v.w) << 16);
            *(uint2*)&ob0[(size_t)grow * N + gcol] = w;
        }
    }
}

// ---------------------------------------------------------------
// 128-tile bf16 MFMA GEMM for QKV (validated rounds 8-17).
// ---------------------------------------------------------------
template <int EPI, int NBUF, int XBY>
__global__ __launch_bounds__(256) void gemm_mfma(
    const ushort_t* __restrict__ A, const ushort_t* __restrict__ Bw,
    const float* __restrict__ bias, int M, int N, int K,
    ushort_t* __restrict__ ob0, ushort_t* __restrict__ ob1)
{
    constexpr int BUFSZ = 8192;
    constexpr int DEPTH = NBUF - 1;
    constexpr int L     = 4;
    constexpr int XBX   = 8 / XBY;
    __shared__ __attribute__((aligned(16))) ushort_t AB[NBUF * BUFSZ];

    const int tid = threadIdx.x;
    const int lane = tid & 63, wid = tid >> 6;
    const int wr = wid >> 1, wc = wid & 1;
    const int l15 = lane & 15, lg = lane >> 4;

    int bx = blockIdx.x, by = blockIdx.y;
    const int gx = gridDim.x, gy = gridDim.y;
    if ((gy % XBY) == 0 && (gx % XBX) == 0) {
        const int s = by * gx + bx;
        const int xcd = s & 7, c = s >> 3;
        const int gyc = gy / XBY, gxc = gx / XBX;
        by = (xcd % XBY) * gyc + (c % gyc);
        bx = (xcd / XBY) * gxc + (c / gyc);
    }
    const int m0 = by * 128, n0 = bx << 7;

    f32x4 acc[4][4];
#pragma unroll
    for (int i = 0; i < 4; ++i)
#pragma unroll
        for (int j = 0; j < 4; ++j) { acc[i][j][0] = 0.f; acc[i][j][1] = 0.f; acc[i][j][2] = 0.f; acc[i][j][3] = 0.f; }

    const int srow4 = lane >> 2;
    const int scc4  = (lane & 3) ^ ((lane >> 3) & 3);
    const ushort_t* Ag = A + (size_t)(m0 + wid * 32 + srow4) * K + scc4 * 8;
    const ushort_t* Bg = Bw + (size_t)(n0 + wid * 32 + srow4) * K + scc4 * 8;

    auto STAGE = [&](int b_, int k0_) {
        ushort_t* d_ = AB + b_ * BUFSZ;
        gload_lds16(Ag + k0_,                  d_ + (wid * 32) * 32);
        gload_lds16(Ag + (size_t)16 * K + k0_, d_ + (wid * 32 + 16) * 32);
        gload_lds16(Bg + k0_,                  d_ + 4096 + (wid * 32) * 32);
        gload_lds16(Bg + (size_t)16 * K + k0_, d_ + 4096 + (wid * 32 + 16) * 32);
    };

    const int NS = K >> 5;
#pragma unroll
    for (int p = 0; p < DEPTH; ++p) STAGE(p, p * 32);
    wait_vm((DEPTH - 1) * L);
    __builtin_amdgcn_s_barrier();

    const int chAB = (lg ^ ((l15 >> 1) & 3)) * 8;
    int bc = 0, bp = DEPTH;
    for (int s = 0; s < NS; ++s) {
        if (s + DEPTH < NS) STAGE(bp, (s + DEPTH) << 5);
        const ushort_t* As_ = AB + bc * BUFSZ;
        const ushort_t* Bs_ = As_ + 4096;
        short8 af[4], bfr[4];
#pragma unroll
        for (int mi = 0; mi < 4; ++mi)
            af[mi] = *(const short8*)&As_[(wr * 64 + mi * 16 + l15) * 32 + chAB];
#pragma unroll
        for (int nj = 0; nj < 4; ++nj)
            bfr[nj] = *(const short8*)&Bs_[(wc * 64 + nj * 16 + l15) * 32 + chAB];
#pragma unroll
        for (int mi = 0; mi < 4; ++mi)
#pragma unroll
            for (int nj = 0; nj < 4; ++nj)
                acc[mi][nj] = __builtin_amdgcn_mfma_f32_16x16x32_bf16(
                    af[mi], bfr[nj], acc[mi][nj], 0, 0, 0);
        if (s + 1 < NS) {
            const int rem = NS - 2 - s;
            wait_vm(((rem < DEPTH - 1) ? rem : DEPTH - 1) * L);
            __builtin_amdgcn_s_barrier();
        }
        bc = (bc + 1 == NBUF) ? 0 : bc + 1;
        bp = (bp + 1 == NBUF) ? 0 : bp + 1;
    }
    __syncthreads();

    // epilogue (bf16 repack; QKV V-blocks transposed to vt)
#pragma unroll
    for (int nj = 0; nj < 4; ++nj) {
        const int coll = wc * 64 + nj * 16 + l15;
        const float bv = bias[n0 + coll];
#pragma unroll
        for (int mi = 0; mi < 4; ++mi)
#pragma unroll
            for (int r = 0; r < 4; ++r)
                AB[(wr * 64 + mi * 16 + lg * 4 + r) * 128 + coll] = f2bf(acc[mi][nj][r] + bv);
    }
    __syncthreads();
    if (EPI == EPI_QKV && n0 >= 2048) {
        const int bb = m0 >> 10, srow0 = m0 & 1023;
#pragma unroll
        for (int it = 0; it < 8; ++it) {
            const int task = it * 256 + tid;
            const int dim = task & 127;
            const int strip = task >> 7;
            uint_t w[4];
#pragma unroll
            for (int j = 0; j < 4; ++j) {
                const int s2 = strip * 8 + 2 * j;
                w[j] = (uint_t)AB[s2 * 128 + dim] | ((uint_t)AB[(s2 + 1) * 128 + dim] << 16);
            }
            const int vd = (n0 - 2048) + dim;
            *(uint4*)&ob1[((size_t)(bb * Hh + (vd >> 6)) * 64 + (vd & 63)) * Ss + srow0 + strip * 8] =
                make_uint4(w[0], w[1], w[2], w[3]);
        }
    } else {
#pragma unroll
        for (int i = 0; i < 8; ++i) {
            const int c = i * 256 + tid;
            const int row = c >> 4, ch = c & 15;
            *(uint4*)&ob0[(size_t)(m0 + row) * N + n0 + ch * 8] =
                *(const uint4*)&AB[row * 128 + ch * 8];
        }
    }
}

// ---------------------------------------------------------------
// per-layer weight fp32 -> bf16 conversion + concat bias (dt++xp)
// ---------------------------------------------------------------
__global__ __launch_bounds__(256) void convert_weights_kernel(
    const float* __restrict__ Win, const float* __restrict__ Wdt,
    const float* __restrict__ Wxp, const float* __restrict__ Wout,
    const float* __restrict__ Wqkv, const float* __restrict__ Wao,
    const float* __restrict__ Wf1, const float* __restrict__ Wf2,
    const float* __restrict__ bdt, const float* __restrict__ bxp,
    ushort_t* __restrict__ dst, float* __restrict__ bcat)
{
    size_t q = (size_t)blockIdx.x * blockDim.x + threadIdx.x;
    if (q < 288) {
#pragma unroll
        for (int j = 0; j < 4; ++j) {
            const int e = (int)q * 4 + j;
            bcat[e] = (e < Dd) ? bdt[e] : ((e < Dd + Nn) ? bxp[e - Dd] : 0.f);
        }
    }
    const size_t stride = (size_t)gridDim.x * blockDim.x;
    for (; q < W_QUADS; q += stride) {
        const size_t e = q * 4;
        float4 v;
        if (e < O_DT)       v = *(const float4*)&Win[e - O_IN];
        else if (e < O_XP)  v = *(const float4*)&Wdt[e - O_DT];
        else if (e < O_OUT) {
            const size_t li = e - O_XP;
            const int row = (int)(li >> 11), colq = (int)(li & 2047);
            v = (row < Nn) ? *(const float4*)&Wxp[(size_t)row * DIi + colq]
                           : make_float4(0.f, 0.f, 0.f, 0.f);
        }
        else if (e < O_QKV) v = *(const float4*)&Wout[e - O_OUT];
        else if (e < O_AO)  v = *(const float4*)&Wqkv[e - O_QKV];
        else if (e < O_F1)  v = *(const float4*)&Wao[e - O_AO];
        else if (e < O_F2)  v = *(const float4*)&Wf1[e - O_F1];
        else                v = *(const float4*)&Wf2[e - O_F2];
        uint2 w;
        w.x = (uint_t)f2bf(v.x) | ((uint_t)f2bf(v.y) << 16);
        w.y = (uint_t)f2bf(v.z) | ((uint_t)f2bf(v.w) << 16);
        *(uint2*)&dst[e] = w;
    }
}

__global__ __launch_bounds__(256) void cvt_f32_bf16_kernel(
    const float* __restrict__ in, ushort_t* __restrict__ out)
{
    const size_t i4 = (size_t)blockIdx.x * blockDim.x + threadIdx.x;
    const float4 v = *(const float4*)&in[i4 * 4];
    uint2 w;
    w.x = (uint_t)f2bf(v.x) | ((uint_t)f2bf(v.y) << 16);
    w.y = (uint_t)f2bf(v.z) | ((uint_t)f2bf(v.w) << 16);
    *(uint2*)&out[i4 * 4] = w;
}

__global__ __launch_bounds__(256) void ln_residual_kernel(
    float* __restrict__ xio, const float* __restrict__ addin,
    const float* __restrict__ g, const float* __restrict__ be,
    ushort_t* __restrict__ xb)
{
    __shared__ float red[8];
    const int tid = threadIdx.x;
    const size_t base = (size_t)blockIdx.x * Dd;
    const float4 xv = *(const float4*)&xio[base + tid * 4];
    const float4 av = *(const float4*)&addin[base + tid * 4];
    float v[4] = {xv.x + av.x, xv.y + av.y, xv.z + av.z, xv.w + av.w};
    float s = v[0] + v[1] + v[2] + v[3];
    float s2 = v[0] * v[0] + v[1] * v[1] + v[2] * v[2] + v[3] * v[3];
#pragma unroll
    for (int off = 32; off; off >>= 1) { s += __shfl_xor(s, off); s2 += __shfl_xor(s2, off); }
    if ((tid & 63) == 0) { red[tid >> 6] = s; red[4 + (tid >> 6)] = s2; }
    __syncthreads();
    const float mu = (red[0] + red[1] + red[2] + red[3]) * (1.f / (float)Dd);
    const float var = (red[4] + red[5] + red[6] + red[7]) * (1.f / (float)Dd) - mu * mu;
    const float rstd = rsqrtf(var + 1e-5f);
    const float4 gv = *(const float4*)&g[tid * 4];
    const float4 bv = *(const float4*)&be[tid * 4];
    float o[4];
    o[0] = (v[0] - mu) * rstd * gv.x + bv.x;
    o[1] = (v[1] - mu) * rstd * gv.y + bv.y;
    o[2] = (v[2] - mu) * rstd * gv.z + bv.z;
    o[3] = (v[3] - mu) * rstd * gv.w + bv.w;
    *(float4*)&xio[base + tid * 4] = make_float4(o[0], o[1], o[2], o[3]);
    uint2 w;
    w.x = (uint_t)f2bf(o[0]) | ((uint_t)f2bf(o[1]) << 16);
    w.y = (uint_t)f2bf(o[2]) | ((uint_t)f2bf(o[3]) << 16);
    *(uint2*)&xb[base + tid * 4] = w;
}

// ---------------------------------------------------------------
// Fused chunked selective scan (round 11: m from partials).
// ---------------------------------------------------------------
__global__ __launch_bounds__(1024) void scan_fused_kernel(
    const float* __restrict__ A_log_l, const float* __restrict__ part,
    const float* __restrict__ u, float* __restrict__ ssum)
{
    __shared__ float Ps[16][64];
    __shared__ float Sl[16][64];
    __shared__ float Cs[16][64];
    __shared__ float Ms[16][64];
    const int b = blockIdx.x;
    const int tid = threadIdx.x;
    const int n = tid & 63, c = tid >> 6;
    const int t0 = b * Ss + c * 64;
    const float Aval = -expf(A_log_l[n]);

    {
        const float* pp = part + (size_t)(t0 + n) * 8;
        float ps = 0.f;
#pragma unroll
        for (int j = 0; j < 8; ++j) ps += pp[j];
        Ms[c][n] = ps * (1.f / 1024.f);
    }
    __syncthreads();

    float S = 0.f, msum = 0.f;
#pragma unroll 8
    for (int t = 0; t < 64; ++t) {
        const float mt = Ms[c][t];
        msum += mt;
        S = fmaf(expf(Aval * mt), S, u[(size_t)(t0 + t) * 128 + n]);
    }
    Ps[c][n] = expf(Aval * msum);
    Sl[c][n] = S;
    __syncthreads();

    if (c == 0) {
        float carry = 0.f;
#pragma unroll
        for (int cc = 0; cc < 16; ++cc) {
            Cs[cc][n] = carry;
            carry = fmaf(Ps[cc][n], carry, Sl[cc][n]);
        }
    }
    __syncthreads();

    float st = Cs[c][n];
#pragma unroll 4
    for (int t = 0; t < 64; ++t) {
        st = fmaf(expf(Aval * Ms[c][t]), st, u[(size_t)(t0 + t) * 128 + n]);
        float r = st;
#pragma unroll
        for (int off = 32; off; off >>= 1) r += __shfl_xor(r, off);
        if (n == 0) ssum[t0 + t] = r;
    }
}

__global__ __launch_bounds__(256) void y_gate_kernel(
    ushort_t* __restrict__ xi, const ushort_t* __restrict__ res,
    const float* __restrict__ ssum)
{
    const size_t i8 = (size_t)blockIdx.x * blockDim.x + threadIdx.x;
    const int t = (int)(i8 >> 8);
    const float sv = ssum[t];
    uint4 xw = *(const uint4*)&xi[i8 * 8];
    const uint4 rw = *(const uint4*)&res[i8 * 8];
    const uint_t xs[4] = {xw.x, xw.y, xw.z, xw.w};
    const uint_t rs[4] = {rw.x, rw.y, rw.z, rw.w};
    uint_t os[4];
#pragma unroll
    for (int j = 0; j < 4; ++j) {
        const float x0 = bf2f(xs[j] & 0xffffu), x1 = bf2f(xs[j] >> 16);
        const float r0 = bf2f(rs[j] & 0xffffu), r1 = bf2f(rs[j] >> 16);
        os[j] = (uint_t)f2bf(sv * x0 * siluf(r0)) | ((uint_t)f2bf(sv * x1 * siluf(r1)) << 16);
    }
    *(uint4*)&xi[i8 * 8] = make_uint4(os[0], os[1], os[2], os[3]);
}

// ---------------------------------------------------------------
// MFMA flash attention (round 16: dbuf K/V + setprio).
// ---------------------------------------------------------------
__global__ __launch_bounds__(256) void attn_mfma_kernel(
    const ushort_t* __restrict__ qkv, const ushort_t* __restrict__ vt,
    ushort_t* __restrict__ out)
{
    __shared__ ushort_t Ks[2][64 * 64];
    __shared__ ushort_t Vs[2][64 * 64];
    __shared__ __attribute__((aligned(16))) ushort_t Pb[4][2560];

    const int tid = threadIdx.x;
    const int lane = tid & 63, wid = tid >> 6;
    const int b = blockIdx.z, h = blockIdx.y;
    const int q0 = blockIdx.x * 128 + wid * 32;
    const int l15 = lane & 15, lg = lane >> 4;
    constexpr float CEXP = 0.125f * 1.44269504f;

    short8 qf[2][2];
#pragma unroll
    for (int mi = 0; mi < 2; ++mi)
#pragma unroll
        for (int kk = 0; kk < 2; ++kk)
            qf[mi][kk] = *(const short8*)&qkv[(size_t)(b * Ss + q0 + mi * 16 + l15) * 3072
                                              + h * 64 + kk * 32 + lg * 8];

    f32x4 oacc[2][4];
#pragma unroll
    for (int mi = 0; mi < 2; ++mi)
#pragma unroll
        for (int nj = 0; nj < 4; ++nj) { oacc[mi][nj][0]=0.f; oacc[mi][nj][1]=0.f; oacc[mi][nj][2]=0.f; oacc[mi][nj][3]=0.f; }
    float lrun[2][4];
#pragma unroll
    for (int mi = 0; mi < 2; ++mi)
#pragma unroll
        for (int r = 0; r < 4; ++r) lrun[mi][r] = 0.f;

    const int srow = lane >> 3;
    const int scc  = (lane & 7) ^ srow;
    const ushort_t* Kg = qkv + (size_t)(b * Ss + wid * 16 + srow) * 3072 + 1024 + h * 64 + scc * 8;
    const ushort_t* Vg = vt + (size_t)((b * Hh + h) * 64 + wid * 16 + srow) * Ss + scc * 8;

    auto STAGE_KV = [&](int buf, int kt) {
#pragma unroll
        for (int j = 0; j < 2; ++j) {
            gload_lds16(Kg + (size_t)(kt * 64 + j * 8) * 3072, Ks[buf] + (wid * 16 + j * 8) * 64);
            gload_lds16(Vg + (size_t)j * 8 * Ss + kt * 64,     Vs[buf] + (wid * 16 + j * 8) * 64);
        }
    };

    constexpr int NT = Ss / 64;
    STAGE_KV(0, 0);
    int cur = 0;
    for (int kt = 0; kt < NT; ++kt) {
        if (kt + 1 < NT) STAGE_KV(cur ^ 1, kt + 1);
        wait_vm((kt + 1 < NT) ? 4 : 0);
        __builtin_amdgcn_s_barrier();

        f32x4 sacc[2][4];
#pragma unroll
        for (int mi = 0; mi < 2; ++mi)
#pragma unroll
            for (int nj = 0; nj < 4; ++nj) { sacc[mi][nj][0]=0.f; sacc[mi][nj][1]=0.f; sacc[mi][nj][2]=0.f; sacc[mi][nj][3]=0.f; }
        __builtin_amdgcn_s_setprio(1);
#pragma unroll
        for (int kk = 0; kk < 2; ++kk) {
            short8 kf[4];
#pragma unroll
            for (int nj = 0; nj < 4; ++nj) {
                const int row = nj * 16 + l15;
                const int ch = (kk * 4 + lg) ^ (row & 7);
                kf[nj] = *(const short8*)&Ks[cur][row * 64 + ch * 8];
            }
#pragma unroll
            for (int mi = 0; mi < 2; ++mi)
#pragma unroll
                for (int nj = 0; nj < 4; ++nj)
                    sacc[mi][nj] = __builtin_amdgcn_mfma_f32_16x16x32_bf16(
                        qf[mi][kk], kf[nj], sacc[mi][nj], 0, 0, 0);
        }
        __builtin_amdgcn_s_setprio(0);

#pragma unroll
        for (int mi = 0; mi < 2; ++mi)
#pragma unroll
            for (int nj = 0; nj < 4; ++nj) {
                const int bi = mi * 2 + (nj >> 1);
                const int chsw = ((nj & 1) * 2 + (l15 >> 3)) ^ lg;
#pragma unroll
                for (int r = 0; r < 4; ++r) {
                    const float p = exp2f(sacc[mi][nj][r] * CEXP);
                    lrun[mi][r] += p;
                    const int q15 = lg * 4 + r;
                    Pb[wid][bi * 640 + q15 * 40 + chsw * 8 + (lane & 7)] = f2bf(p);
                }
            }

        __builtin_amdgcn_s_setprio(1);
#pragma unroll
        for (int kk = 0; kk < 2; ++kk) {
            short8 pa[2], vb[4];
#pragma unroll
            for (int mi = 0; mi < 2; ++mi) {
                const int chsw = lg ^ (l15 >> 2);
                pa[mi] = *(const short8*)&Pb[wid][(mi * 2 + kk) * 640 + l15 * 40 + chsw * 8];
            }
#pragma unroll
            for (int nj = 0; nj < 4; ++nj) {
                const int row = nj * 16 + l15;
                const int ch = (kk * 4 + lg) ^ (row & 7);
                vb[nj] = *(const short8*)&Vs[cur][row * 64 + ch * 8];
            }
#pragma unroll
            for (int mi = 0; mi < 2; ++mi)
#pragma unroll
                for (int nj = 0; nj < 4; ++nj)
                    oacc[mi][nj] = __builtin_amdgcn_mfma_f32_16x16x32_bf16(
                        pa[mi], vb[nj], oacc[mi][nj], 0, 0, 0);
        }
        __builtin_amdgcn_s_setprio(0);

        asm volatile("s_waitcnt lgkmcnt(0)" ::: "memory");
        __builtin_amdgcn_s_barrier();
        cur ^= 1;
    }

#pragma unroll
    for (int mi = 0; mi < 2; ++mi)
#pragma unroll
        for (int r = 0; r < 4; ++r) {
            float s = lrun[mi][r];
#pragma unroll
            for (int off = 1; off < 16; off <<= 1) s += __shfl_xor(s, off);
            lrun[mi][r] = 1.f / s;
        }
#pragma unroll
    for (int mi = 0; mi < 2; ++mi)
#pragma unroll
        for (int r = 0; r < 4; ++r) {
            const int q = q0 + mi * 16 + lg * 4 + r;
            const float inv = lrun[mi][r];
#pragma unroll
            for (int nj = 0; nj < 4; ++nj)
                out[(size_t)(b * Ss + q) * Dd + h * 64 + nj * 16 + l15] =
                    f2bf(oacc[mi][nj][r] * inv);
        }
}

// ---------------------------------------------------------------
extern "C" void kernel_launch(void* const* d_in, const int* in_sizes, int n_in,
                              void* d_out, int out_size, void* d_ws, size_t ws_size,
                              hipStream_t stream)
{
    const float* x_in  = (const float*)d_in[0];
    const float* A_log = (const float*)d_in[1];
    const float* Dp    = (const float*)d_in[2];
    const float* W_in  = (const float*)d_in[3];
    const float* b_in  = (const float*)d_in[4];
    const float* W_xp  = (const float*)d_in[5];
    const float* b_xp  = (const float*)d_in[6];
    const float* W_dt  = (const float*)d_in[7];
    const float* b_dt  = (const float*)d_in[8];
    const float* W_out = (const float*)d_in[9];
    const float* b_out = (const float*)d_in[10];
    const float* W_qkv = (const float*)d_in[11];
    const float* b_qkv = (const float*)d_in[12];
    const float* W_ao  = (const float*)d_in[13];
    const float* b_ao  = (const float*)d_in[14];
    const float* g1    = (const float*)d_in[15];
    const float* be1   = (const float*)d_in[16];
    const float* g2    = (const float*)d_in[17];
    const float* be2   = (const float*)d_in[18];
    const float* W_f1  = (const float*)d_in[19];
    const float* b_f1  = (const float*)d_in[20];
    const float* W_f2  = (const float*)d_in[21];
    const float* b_f2  = (const float*)d_in[22];

    // ---- workspace layout ----
    float* xf      = (float*)d_ws;                  // 4M f32 residual stream
    float* a3      = xf + 4194304;                  // 4M f32 mo/po
    float* ub      = a3 + 4194304;                  // 4096*128 f32 (padded u)
    float* sb      = ub + 524288;                   // 4096
    float* part    = sb + 4096;                     // 4096*8 delta row partials
    float* bcat    = part + 32768;                  // 1152
    ushort_t* xb    = (ushort_t*)(bcat + 1152);     // 4M bf16
    ushort_t* xi_b  = xb + 4194304;                 // 8M bf16 (xi -> y)
    ushort_t* res_b = xi_b + 8388608;               // 8M bf16
    ushort_t* qh_b  = res_b + 8388608;              // 16M bf16 (qkv / ffn hidden)
    ushort_t* ao_b  = qh_b + 16777216;              // 4M bf16
    ushort_t* Wb    = ao_b + 4194304;               // 21.23M bf16 weights
    ushort_t* vt_b  = Wb + W_TOTAL;                 // 4M bf16 (V transposed)

    hipMemcpyAsync(xf, x_in, (size_t)TOKENS * Dd * sizeof(float),
                   hipMemcpyDeviceToDevice, stream);
    cvt_f32_bf16_kernel<<<dim3(4096), dim3(256), 0, stream>>>(x_in, xb);

    const dim3 blk(256), blk512(512);

    for (int l = 0; l < 4; ++l) {
        convert_weights_kernel<<<dim3(2048), blk, 0, stream>>>(
            W_in + (size_t)l * 4194304, W_dt + (size_t)l * 2097152,
            W_xp + (size_t)l * 131072,  W_out + (size_t)l * 2097152,
            W_qkv + (size_t)l * 3145728, W_ao + (size_t)l * 1048576,
            W_f1 + (size_t)l * 4194304, W_f2 + (size_t)l * 4194304,
            b_dt + (size_t)l * 1024, b_xp + (size_t)l * Nn, Wb, bcat);

        // 1) xr = x @ W_in^T: silu half -> xi_b, raw half -> res_b (256^2, T4)
        gemm_wide256<EPI_SPLIT><<<dim3(16, 16), blk512, 0, stream>>>(
            xb, Wb + O_IN, b_in + (size_t)l * 4096, TOKENS, 4096, 1024,
            xi_b, res_b);
        // 2+3+4) fused: [delta|u]; delta -> row partials (part), u -> ub
        gemm_narrow64<EPI_DTXP, 8><<<dim3(9, 64), blk, 0, stream>>>(
            xi_b, Wb + O_DT, bcat, TOKENS, 1152, 2048,
            part, ub, nullptr, nullptr, nullptr);
        // 5) fused chunked scan -> sb
        scan_fused_kernel<<<dim3(Bb), dim3(1024), 0, stream>>>(
            A_log + (size_t)l * Nn, part, ub, sb);
        // 6) y = ssum * xi * silu(res) (in place, bf16)
        y_gate_kernel<<<dim3(4096), blk, 0, stream>>>(xi_b, res_b, sb);
        // 7) mamba_out = y @ W_out^T + x*Dp -> a3 (fp32)
        gemm_narrow64<EPI_DP, 8><<<dim3(8, 64), blk, 0, stream>>>(
            xi_b, Wb + O_OUT, b_out + (size_t)l * 1024, TOKENS, 1024, 2048,
            a3, nullptr, nullptr, xf, Dp + (size_t)l * 1024);
        // 8) x = LN(x + mamba_out)
        ln_residual_kernel<<<dim3(TOKENS), blk, 0, stream>>>(
            xf, a3, g1 + (size_t)l * 1024, be1 + (size_t)l * 1024, xb);
        // 9) qkv = x @ W_qkv^T; K/Q -> qh_b, V transposed -> vt_b (128^2)
        gemm_mfma<EPI_QKV, 3, 4><<<dim3(24, 32), blk, 0, stream>>>(
            xb, Wb + O_QKV, b_qkv + (size_t)l * 3072, TOKENS, 3072, 1024,
            qh_b, vt_b);
        // 10) MFMA flash attention (dbuf K/V) -> ao_b
        attn_mfma_kernel<<<dim3(8, Hh, Bb), blk, 0, stream>>>(qh_b, vt_b, ao_b);
        // 11) proj = attn @ W_ao^T -> a3 (fp32)
        gemm_narrow64<EPI_F32, 8><<<dim3(8, 64), blk, 0, stream>>>(
            ao_b, Wb + O_AO, b_ao + (size_t)l * 1024, TOKENS, 1024, 1024,
            a3, nullptr, nullptr, nullptr, nullptr);
        // 12) x = LN(x + proj)
        ln_residual_kernel<<<dim3(TOKENS), blk, 0, stream>>>(
            xf, a3, g2 + (size_t)l * 1024, be2 + (size_t)l * 1024, xb);
        // 13) h = gelu(x @ W_f1^T) -> qh_b (256^2, T4)
        gemm_wide256<EPI_GELU><<<dim3(16, 16), blk512, 0, stream>>>(
            xb, Wb + O_F1, b_f1 + (size_t)l * 4096, TOKENS, 4096, 1024,
            qh_b, nullptr);
        // 14) x = x + h @ W_f2^T (fp32 in place) and xb (bf16)
        gemm_narrow64<EPI_RESID, 8><<<dim3(8, 64), blk, 0, stream>>>(
            qh_b, Wb + O_F2, b_f2 + (size_t)l * 1024, TOKENS, 1024, 4096,
            xf, nullptr, xb, xf, nullptr);
    }

    hipMemcpyAsync(d_out, xf, (size_t)TOKENS * Dd * sizeof(float),
                   hipMemcpyDeviceToDevice, stream);
    (void)in_sizes; (void)n_in; (void)out_size; (void)ws_size;
}

// Round 19
// 1624.796 us; speedup vs baseline: 1.0092x; 1.0092x over previous
//
#include <hip/hip_runtime.h>
#include <math.h>

typedef unsigned short ushort_t;
typedef unsigned int uint_t;
typedef __attribute__((ext_vector_type(8))) short short8;
typedef __attribute__((ext_vector_type(4))) float f32x4;

// ---------------- problem constants ----------------
constexpr int Bb = 4, Ss = 1024, Dd = 1024, Nn = 64, Hh = 16;
constexpr int DIi = 2048, DFf = 4096;
constexpr int TOKENS = Bb * Ss;          // 4096

// per-layer bf16 weight arena segment offsets (in elements)
constexpr size_t O_IN  = 0;                         // 4096x1024
constexpr size_t O_DT  = 4194304;                   // 1152x2048 (W_dt ++ W_xp padded)
constexpr size_t O_XP  = O_DT + 2097152;            // (xp rows live here)
constexpr size_t O_OUT = O_XP + 262144;             // 1024x2048
constexpr size_t O_QKV = O_OUT + 2097152;           // 3072x1024
constexpr size_t O_AO  = O_QKV + 3145728;           // 1024x1024
constexpr size_t O_F1  = O_AO + 1048576;            // 4096x1024
constexpr size_t O_F2  = O_F1 + 4194304;            // 1024x4096
constexpr size_t W_TOTAL = O_F2 + 4194304;          // 21,233,664
constexpr size_t W_QUADS = W_TOTAL / 4;             // 5,308,416

enum { EPI_SPLIT = 0, EPI_QKV, EPI_GELU, EPI_DTXP, EPI_DP, EPI_F32, EPI_RESID };

__device__ __forceinline__ float siluf(float x) { return x / (1.f + expf(-x)); }
__device__ __forceinline__ float softplusf(float x) { return fmaxf(x, 0.f) + log1pf(expf(-fabsf(x))); }
__device__ __forceinline__ float geluf(float x) { return 0.5f * x * (1.f + erff(x * 0.7071067811865476f)); }

__device__ __forceinline__ float bf2f(uint_t u) {
    union { uint_t i; float f; } v; v.i = u << 16; return v.f;
}
__device__ __forceinline__ ushort_t f2bf(float f) {   // RNE
    union { float f; uint_t i; } v; v.f = f;
    return (ushort_t)((v.i + 0x7FFFu + ((v.i >> 16) & 1u)) >> 16);
}

__device__ __forceinline__ void gload_lds16(const ushort_t* g, ushort_t* l) {
    __builtin_amdgcn_global_load_lds(
        (const __attribute__((address_space(1))) unsigned int*)g,
        (__attribute__((address_space(3))) unsigned int*)l, 16, 0, 0);
}

__device__ __forceinline__ void wait_vm(int n) {
    if (n == 0)      asm volatile("s_waitcnt vmcnt(0)" ::: "memory");
    else if (n == 4) asm volatile("s_waitcnt vmcnt(4)" ::: "memory");
    else if (n == 8) asm volatile("s_waitcnt vmcnt(8)" ::: "memory");
    else             asm volatile("s_waitcnt vmcnt(0)" ::: "memory");
}

// ---------------------------------------------------------------
// 256x256-tile BK=64 bf16 GEMM for SPLIT/GELU (round-17 validated:
// 55.5us, best measured). 512 thr = 8 waves (2Mx4N), wave owns
// 128x64 = 64 MFMA per K-tile; double-buffered 128KB LDS; one
// vmcnt(0)+barrier per K-tile (64 MFMA amortize the drain).
// Round-18's counted-vmcnt half-K variant REVERTED (regressed:
// halved MFMA/barrier dominated the counted-wait gain).
// ---------------------------------------------------------------
template <int EPI>
__global__ __launch_bounds__(512, 2) void gemm_wide256(
    const ushort_t* __restrict__ A, const ushort_t* __restrict__ Bw,
    const float* __restrict__ bias, int M, int N, int K,
    ushort_t* __restrict__ ob0, ushort_t* __restrict__ ob1)
{
    __shared__ __attribute__((aligned(16))) ushort_t AB[65536];   // 128KB
    const int tid = threadIdx.x;
    const int lane = tid & 63, wid = tid >> 6;
    const int wr = wid >> 2, wc = wid & 3;
    const int l15 = lane & 15, lg = lane >> 4;

    int bx = blockIdx.x, by = blockIdx.y;
    const int gx = gridDim.x, gy = gridDim.y;
    if ((gy & 3) == 0 && (gx & 1) == 0) {
        const int s = by * gx + bx;
        const int xcd = s & 7, c = s >> 3;
        const int gyc = gy >> 2, gxc = gx >> 1;
        by = (xcd & 3) * gyc + (c % gyc);
        bx = (xcd >> 2) * gxc + (c / gyc);
    }
    const int m0 = by << 8, n0 = bx << 8;

    f32x4 acc[8][4];
#pragma unroll
    for (int i = 0; i < 8; ++i)
#pragma unroll
        for (int j = 0; j < 4; ++j) { acc[i][j][0]=0.f; acc[i][j][1]=0.f; acc[i][j][2]=0.f; acc[i][j][3]=0.f; }

    const int srow8 = lane >> 3;
    const int scc8  = (lane & 7) ^ srow8;
    const ushort_t* Ag = A + (size_t)(m0 + wid * 32 + srow8) * K + scc8 * 8;
    const ushort_t* Bg = Bw + (size_t)(n0 + wid * 32 + srow8) * K + scc8 * 8;

    auto STAGE = [&](int b_, int k0_) {
        ushort_t* d_ = AB + b_ * 32768;
#pragma unroll
        for (int i = 0; i < 4; ++i) {
            gload_lds16(Ag + (size_t)i * 8 * K + k0_, d_ + (wid * 32 + i * 8) * 64);
            gload_lds16(Bg + (size_t)i * 8 * K + k0_, d_ + 16384 + (wid * 32 + i * 8) * 64);
        }
    };

    const int NS = K >> 6;
    STAGE(0, 0);
    wait_vm(0);
    __builtin_amdgcn_s_barrier();
    int cur = 0;
    for (int s = 0; s < NS; ++s) {
        if (s + 1 < NS) STAGE(cur ^ 1, (s + 1) << 6);
        const ushort_t* As_ = AB + cur * 32768;
        const ushort_t* Bs_ = As_ + 16384;
#pragma unroll
        for (int kk = 0; kk < 2; ++kk) {
            short8 af[8], bfr[4];
#pragma unroll
            for (int mi = 0; mi < 8; ++mi) {
                const int row = wr * 128 + mi * 16 + l15;
                const int ch = (kk * 4 + lg) ^ (row & 7);
                af[mi] = *(const short8*)&As_[row * 64 + ch * 8];
            }
#pragma unroll
            for (int nj = 0; nj < 4; ++nj) {
                const int row = wc * 64 + nj * 16 + l15;
                const int ch = (kk * 4 + lg) ^ (row & 7);
                bfr[nj] = *(const short8*)&Bs_[row * 64 + ch * 8];
            }
#pragma unroll
            for (int mi = 0; mi < 8; ++mi)
#pragma unroll
                for (int nj = 0; nj < 4; ++nj)
                    acc[mi][nj] = __builtin_amdgcn_mfma_f32_16x16x32_bf16(
                        af[mi], bfr[nj], acc[mi][nj], 0, 0, 0);
        }
        if (s + 1 < NS) {
            wait_vm(0);
            __builtin_amdgcn_s_barrier();
        }
        cur ^= 1;
    }
    __syncthreads();

    // ---- epilogue: C [256][256] bf16 = 128KB, single pass ----
    const bool lo = (EPI != EPI_SPLIT) || (n0 < DIi);
#pragma unroll
    for (int nj = 0; nj < 4; ++nj) {
        const int coll = wc * 64 + nj * 16 + l15;
        const float bv = bias[n0 + coll];
#pragma unroll
        for (int mi = 0; mi < 8; ++mi)
#pragma unroll
            for (int r = 0; r < 4; ++r) {
                float v = acc[mi][nj][r] + bv;
                if (EPI == EPI_SPLIT) v = lo ? siluf(v) : v;
                else v = geluf(v);
                AB[(wr * 128 + mi * 16 + lg * 4 + r) * 256 + coll] = f2bf(v);
            }
    }
    __syncthreads();
    ushort_t* dst = (EPI == EPI_SPLIT) ? (lo ? ob0 : ob1) : ob0;
    const int Nd = (EPI == EPI_SPLIT) ? DIi : N;
    const int nb = (EPI == EPI_SPLIT && !lo) ? (n0 - DIi) : n0;
#pragma unroll
    for (int it = 0; it < 16; ++it) {
        const int c = it * 512 + tid;
        const int row = c >> 5, ch = c & 31;
        *(uint4*)&dst[(size_t)(m0 + row) * Nd + nb + ch * 8] =
            *(const uint4*)&AB[row * 256 + ch * 8];
    }
}

// ---------------------------------------------------------------
// 64x128-tile BK=64 bf16 GEMM for the narrow (N<=1152) GEMMs
// (validated round 17).
// ---------------------------------------------------------------
template <int EPI, int XBY>
__global__ __launch_bounds__(256) void gemm_narrow64(
    const ushort_t* __restrict__ A, const ushort_t* __restrict__ Bw,
    const float* __restrict__ bias, int M, int N, int K,
    float* __restrict__ of0, float* __restrict__ of1,
    ushort_t* __restrict__ ob0,
    const float* __restrict__ e0, const float* __restrict__ e1)
{
    constexpr int BUFSZ = 12288;     // A 64x64 (4096) + B 128x64 (8192) ushorts
    __shared__ __attribute__((aligned(16))) ushort_t AB[2 * BUFSZ];   // 48KB

    const int tid = threadIdx.x;
    const int lane = tid & 63, wid = tid >> 6;
    const int wc = wid;
    const int l15 = lane & 15, lg = lane >> 4;
    constexpr int XBX = 8 / XBY;

    int bx = blockIdx.x, by = blockIdx.y;
    const int gx = gridDim.x, gy = gridDim.y;
    if ((gy % XBY) == 0 && (gx % XBX) == 0) {
        const int s = by * gx + bx;
        const int xcd = s & 7, c = s >> 3;
        const int gyc = gy / XBY, gxc = gx / XBX;
        by = (xcd % XBY) * gyc + (c % gyc);
        bx = (xcd / XBY) * gxc + (c / gyc);
    }
    const int m0 = by * 64, n0 = bx << 7;

    f32x4 acc[4][2];
#pragma unroll
    for (int i = 0; i < 4; ++i)
#pragma unroll
        for (int j = 0; j < 2; ++j) { acc[i][j][0]=0.f; acc[i][j][1]=0.f; acc[i][j][2]=0.f; acc[i][j][3]=0.f; }

    const int srow8 = lane >> 3;
    const int scc8  = (lane & 7) ^ srow8;
    const ushort_t* sb[6];
    int dofs[6];
#pragma unroll
    for (int j = 0; j < 6; ++j) {
        const int i = wid * 6 + j;
        const bool isA = i < 8;
        const int rb = (isA ? i : i - 8) * 8;
        sb[j] = (isA ? A + (size_t)(m0 + rb + srow8) * K
                     : Bw + (size_t)(n0 + rb + srow8) * K) + scc8 * 8;
        dofs[j] = (isA ? 0 : 4096) + rb * 64;
    }

    auto STAGE = [&](int b_, int k0_) {
        ushort_t* d_ = AB + b_ * BUFSZ;
#pragma unroll
        for (int j = 0; j < 6; ++j)
            gload_lds16(sb[j] + k0_, d_ + dofs[j]);
    };

    const int NS = K >> 6;
    STAGE(0, 0);
    wait_vm(0);
    __builtin_amdgcn_s_barrier();
    int cur = 0;
    for (int s = 0; s < NS; ++s) {
        if (s + 1 < NS) STAGE(cur ^ 1, (s + 1) << 6);
        const ushort_t* As_ = AB + cur * BUFSZ;
        const ushort_t* Bs_ = As_ + 4096;
#pragma unroll
        for (int kk = 0; kk < 2; ++kk) {
            short8 af[4], bfr[2];
#pragma unroll
            for (int mi = 0; mi < 4; ++mi) {
                const int row = mi * 16 + l15;
                const int ch = (kk * 4 + lg) ^ (row & 7);
                af[mi] = *(const short8*)&As_[row * 64 + ch * 8];
            }
#pragma unroll
            for (int nj = 0; nj < 2; ++nj) {
                const int row = wc * 32 + nj * 16 + l15;
                const int ch = (kk * 4 + lg) ^ (row & 7);
                bfr[nj] = *(const short8*)&Bs_[row * 64 + ch * 8];
            }
#pragma unroll
            for (int mi = 0; mi < 4; ++mi)
#pragma unroll
                for (int nj = 0; nj < 2; ++nj)
                    acc[mi][nj] = __builtin_amdgcn_mfma_f32_16x16x32_bf16(
                        af[mi], bfr[nj], acc[mi][nj], 0, 0, 0);
        }
        if (s + 1 < NS) {
            wait_vm(0);
            __builtin_amdgcn_s_barrier();
        }
        cur ^= 1;
    }
    __syncthreads();

    // ---- epilogue: C 64x128 f32 = 32KB in AB; single pass ----
    float* Cf = (float*)AB;
#pragma unroll
    for (int nj = 0; nj < 2; ++nj) {
        const int coll = wc * 32 + nj * 16 + l15;
        const float bv = bias[n0 + coll];
#pragma unroll
        for (int mi = 0; mi < 4; ++mi)
#pragma unroll
            for (int r = 0; r < 4; ++r)
                Cf[(mi * 16 + lg * 4 + r) * 128 + coll] = acc[mi][nj][r] + bv;
    }
    __syncthreads();
#pragma unroll
    for (int i = 0; i < 8; ++i) {
        const int c = i * 256 + tid;
        const int row = c >> 5, ch = c & 31;
        const int grow = m0 + row;
        const int gcol = n0 + ch * 4;
        float4 v = *(const float4*)&Cf[row * 128 + ch * 4];
        if (EPI == EPI_DTXP) {
            if (n0 < Dd) {
                float ps = softplusf(v.x) + softplusf(v.y) + softplusf(v.z) + softplusf(v.w);
#pragma unroll
                for (int off = 1; off < 32; off <<= 1) ps += __shfl_xor(ps, off);
                if ((lane & 31) == 0)
                    of0[(size_t)grow * 8 + (n0 >> 7)] = ps;
            } else {
                *(float4*)&of1[(size_t)grow * 128 + (gcol - Dd)] = v;
            }
        } else if (EPI == EPI_DP) {
            const float4 e = *(const float4*)&e0[(size_t)grow * N + gcol];
            const float4 d = *(const float4*)&e1[gcol];
            v.x = fmaf(e.x, d.x, v.x); v.y = fmaf(e.y, d.y, v.y);
            v.z = fmaf(e.z, d.z, v.z); v.w = fmaf(e.w, d.w, v.w);
            *(float4*)&of0[(size_t)grow * N + gcol] = v;
        } else if (EPI == EPI_F32) {
            *(float4*)&of0[(size_t)grow * N + gcol] = v;
        } else {              // EPI_RESID: +e0 -> of0 (f32) and ob0 (bf16)
            const float4 e = *(const float4*)&e0[(size_t)grow * N + gcol];
            v.x += e.x; v.y += e.y; v.z += e.z; v.w += e.w;
            *(float4*)&of0[(size_t)grow * N + gcol] = v;
            uint2 w;
            w.x = (uint_t)f2bf(v.x) | ((uint_t)f2bf(v.y) << 16);
            w.y = (uint_t)f2bf(v.z) | ((uint_t)f2bf(v.w) << 16);
            *(uint2*)&ob0[(size_t)grow * N + gcol] = w;
        }
    }
}

// ---------------------------------------------------------------
// 128-tile bf16 MFMA GEMM for QKV (validated rounds 8-17).
// ---------------------------------------------------------------
template <int EPI, int NBUF, int XBY>
__global__ __launch_bounds__(256) void gemm_mfma(
    const ushort_t* __restrict__ A, const ushort_t* __restrict__ Bw,
    const float* __restrict__ bias, int M, int N, int K,
    ushort_t* __restrict__ ob0, ushort_t* __restrict__ ob1)
{
    constexpr int BUFSZ = 8192;
    constexpr int DEPTH = NBUF - 1;
    constexpr int L     = 4;
    constexpr int XBX   = 8 / XBY;
    __shared__ __attribute__((aligned(16))) ushort_t AB[NBUF * BUFSZ];

    const int tid = threadIdx.x;
    const int lane = tid & 63, wid = tid >> 6;
    const int wr = wid >> 1, wc = wid & 1;
    const int l15 = lane & 15, lg = lane >> 4;

    int bx = blockIdx.x, by = blockIdx.y;
    const int gx = gridDim.x, gy = gridDim.y;
    if ((gy % XBY) == 0 && (gx % XBX) == 0) {
        const int s = by * gx + bx;
        const int xcd = s & 7, c = s >> 3;
        const int gyc = gy / XBY, gxc = gx / XBX;
        by = (xcd % XBY) * gyc + (c % gyc);
        bx = (xcd / XBY) * gxc + (c / gyc);
    }
    const int m0 = by * 128, n0 = bx << 7;

    f32x4 acc[4][4];
#pragma unroll
    for (int i = 0; i < 4; ++i)
#pragma unroll
        for (int j = 0; j < 4; ++j) { acc[i][j][0] = 0.f; acc[i][j][1] = 0.f; acc[i][j][2] = 0.f; acc[i][j][3] = 0.f; }

    const int srow4 = lane >> 2;
    const int scc4  = (lane & 3) ^ ((lane >> 3) & 3);
    const ushort_t* Ag = A + (size_t)(m0 + wid * 32 + srow4) * K + scc4 * 8;
    const ushort_t* Bg = Bw + (size_t)(n0 + wid * 32 + srow4) * K + scc4 * 8;

    auto STAGE = [&](int b_, int k0_) {
        ushort_t* d_ = AB + b_ * BUFSZ;
        gload_lds16(Ag + k0_,                  d_ + (wid * 32) * 32);
        gload_lds16(Ag + (size_t)16 * K + k0_, d_ + (wid * 32 + 16) * 32);
        gload_lds16(Bg + k0_,                  d_ + 4096 + (wid * 32) * 32);
        gload_lds16(Bg + (size_t)16 * K + k0_, d_ + 4096 + (wid * 32 + 16) * 32);
    };

    const int NS = K >> 5;
#pragma unroll
    for (int p = 0; p < DEPTH; ++p) STAGE(p, p * 32);
    wait_vm((DEPTH - 1) * L);
    __builtin_amdgcn_s_barrier();

    const int chAB = (lg ^ ((l15 >> 1) & 3)) * 8;
    int bc = 0, bp = DEPTH;
    for (int s = 0; s < NS; ++s) {
        if (s + DEPTH < NS) STAGE(bp, (s + DEPTH) << 5);
        const ushort_t* As_ = AB + bc * BUFSZ;
        const ushort_t* Bs_ = As_ + 4096;
        short8 af[4], bfr[4];
#pragma unroll
        for (int mi = 0; mi < 4; ++mi)
            af[mi] = *(const short8*)&As_[(wr * 64 + mi * 16 + l15) * 32 + chAB];
#pragma unroll
        for (int nj = 0; nj < 4; ++nj)
            bfr[nj] = *(const short8*)&Bs_[(wc * 64 + nj * 16 + l15) * 32 + chAB];
#pragma unroll
        for (int mi = 0; mi < 4; ++mi)
#pragma unroll
            for (int nj = 0; nj < 4; ++nj)
                acc[mi][nj] = __builtin_amdgcn_mfma_f32_16x16x32_bf16(
                    af[mi], bfr[nj], acc[mi][nj], 0, 0, 0);
        if (s + 1 < NS) {
            const int rem = NS - 2 - s;
            wait_vm(((rem < DEPTH - 1) ? rem : DEPTH - 1) * L);
            __builtin_amdgcn_s_barrier();
        }
        bc = (bc + 1 == NBUF) ? 0 : bc + 1;
        bp = (bp + 1 == NBUF) ? 0 : bp + 1;
    }
    __syncthreads();

    // epilogue (bf16 repack; QKV V-blocks transposed to vt)
#pragma unroll
    for (int nj = 0; nj < 4; ++nj) {
        const int coll = wc * 64 + nj * 16 + l15;
        const float bv = bias[n0 + coll];
#pragma unroll
        for (int mi = 0; mi < 4; ++mi)
#pragma unroll
            for (int r = 0; r < 4; ++r)
                AB[(wr * 64 + mi * 16 + lg * 4 + r) * 128 + coll] = f2bf(acc[mi][nj][r] + bv);
    }
    __syncthreads();
    if (EPI == EPI_QKV && n0 >= 2048) {
        const int bb = m0 >> 10, srow0 = m0 & 1023;
#pragma unroll
        for (int it = 0; it < 8; ++it) {
            const int task = it * 256 + tid;
            const int dim = task & 127;
            const int strip = task >> 7;
            uint_t w[4];
#pragma unroll
            for (int j = 0; j < 4; ++j) {
                const int s2 = strip * 8 + 2 * j;
                w[j] = (uint_t)AB[s2 * 128 + dim] | ((uint_t)AB[(s2 + 1) * 128 + dim] << 16);
            }
            const int vd = (n0 - 2048) + dim;
            *(uint4*)&ob1[((size_t)(bb * Hh + (vd >> 6)) * 64 + (vd & 63)) * Ss + srow0 + strip * 8] =
                make_uint4(w[0], w[1], w[2], w[3]);
        }
    } else {
#pragma unroll
        for (int i = 0; i < 8; ++i) {
            const int c = i * 256 + tid;
            const int row = c >> 4, ch = c & 15;
            *(uint4*)&ob0[(size_t)(m0 + row) * N + n0 + ch * 8] =
                *(const uint4*)&AB[row * 128 + ch * 8];
        }
    }
}

// ---------------------------------------------------------------
// per-layer weight fp32 -> bf16 conversion + concat bias (dt++xp)
// ---------------------------------------------------------------
__global__ __launch_bounds__(256) void convert_weights_kernel(
    const float* __restrict__ Win, const float* __restrict__ Wdt,
    const float* __restrict__ Wxp, const float* __restrict__ Wout,
    const float* __restrict__ Wqkv, const float* __restrict__ Wao,
    const float* __restrict__ Wf1, const float* __restrict__ Wf2,
    const float* __restrict__ bdt, const float* __restrict__ bxp,
    ushort_t* __restrict__ dst, float* __restrict__ bcat)
{
    size_t q = (size_t)blockIdx.x * blockDim.x + threadIdx.x;
    if (q < 288) {
#pragma unroll
        for (int j = 0; j < 4; ++j) {
            const int e = (int)q * 4 + j;
            bcat[e] = (e < Dd) ? bdt[e] : ((e < Dd + Nn) ? bxp[e - Dd] : 0.f);
        }
    }
    const size_t stride = (size_t)gridDim.x * blockDim.x;
    for (; q < W_QUADS; q += stride) {
        const size_t e = q * 4;
        float4 v;
        if (e < O_DT)       v = *(const float4*)&Win[e - O_IN];
        else if (e < O_XP)  v = *(const float4*)&Wdt[e - O_DT];
        else if (e < O_OUT) {
            const size_t li = e - O_XP;
            const int row = (int)(li >> 11), colq = (int)(li & 2047);
            v = (row < Nn) ? *(const float4*)&Wxp[(size_t)row * DIi + colq]
                           : make_float4(0.f, 0.f, 0.f, 0.f);
        }
        else if (e < O_QKV) v = *(const float4*)&Wout[e - O_OUT];
        else if (e < O_AO)  v = *(const float4*)&Wqkv[e - O_QKV];
        else if (e < O_F1)  v = *(const float4*)&Wao[e - O_AO];
        else if (e < O_F2)  v = *(const float4*)&Wf1[e - O_F1];
        else                v = *(const float4*)&Wf2[e - O_F2];
        uint2 w;
        w.x = (uint_t)f2bf(v.x) | ((uint_t)f2bf(v.y) << 16);
        w.y = (uint_t)f2bf(v.z) | ((uint_t)f2bf(v.w) << 16);
        *(uint2*)&dst[e] = w;
    }
}

__global__ __launch_bounds__(256) void cvt_f32_bf16_kernel(
    const float* __restrict__ in, ushort_t* __restrict__ out)
{
    const size_t i4 = (size_t)blockIdx.x * blockDim.x + threadIdx.x;
    const float4 v = *(const float4*)&in[i4 * 4];
    uint2 w;
    w.x = (uint_t)f2bf(v.x) | ((uint_t)f2bf(v.y) << 16);
    w.y = (uint_t)f2bf(v.z) | ((uint_t)f2bf(v.w) << 16);
    *(uint2*)&out[i4 * 4] = w;
}

__global__ __launch_bounds__(256) void ln_residual_kernel(
    float* __restrict__ xio, const float* __restrict__ addin,
    const float* __restrict__ g, const float* __restrict__ be,
    ushort_t* __restrict__ xb)
{
    __shared__ float red[8];
    const int tid = threadIdx.x;
    const size_t base = (size_t)blockIdx.x * Dd;
    const float4 xv = *(const float4*)&xio[base + tid * 4];
    const float4 av = *(const float4*)&addin[base + tid * 4];
    float v[4] = {xv.x + av.x, xv.y + av.y, xv.z + av.z, xv.w + av.w};
    float s = v[0] + v[1] + v[2] + v[3];
    float s2 = v[0] * v[0] + v[1] * v[1] + v[2] * v[2] + v[3] * v[3];
#pragma unroll
    for (int off = 32; off; off >>= 1) { s += __shfl_xor(s, off); s2 += __shfl_xor(s2, off); }
    if ((tid & 63) == 0) { red[tid >> 6] = s; red[4 + (tid >> 6)] = s2; }
    __syncthreads();
    const float mu = (red[0] + red[1] + red[2] + red[3]) * (1.f / (float)Dd);
    const float var = (red[4] + red[5] + red[6] + red[7]) * (1.f / (float)Dd) - mu * mu;
    const float rstd = rsqrtf(var + 1e-5f);
    const float4 gv = *(const float4*)&g[tid * 4];
    const float4 bv = *(const float4*)&be[tid * 4];
    float o[4];
    o[0] = (v[0] - mu) * rstd * gv.x + bv.x;
    o[1] = (v[1] - mu) * rstd * gv.y + bv.y;
    o[2] = (v[2] - mu) * rstd * gv.z + bv.z;
    o[3] = (v[3] - mu) * rstd * gv.w + bv.w;
    *(float4*)&xio[base + tid * 4] = make_float4(o[0], o[1], o[2], o[3]);
    uint2 w;
    w.x = (uint_t)f2bf(o[0]) | ((uint_t)f2bf(o[1]) << 16);
    w.y = (uint_t)f2bf(o[2]) | ((uint_t)f2bf(o[3]) << 16);
    *(uint2*)&xb[base + tid * 4] = w;
}

// ---------------------------------------------------------------
// Fused chunked selective scan (round 11: m from partials).
// ---------------------------------------------------------------
__global__ __launch_bounds__(1024) void scan_fused_kernel(
    const float* __restrict__ A_log_l, const float* __restrict__ part,
    const float* __restrict__ u, float* __restrict__ ssum)
{
    __shared__ float Ps[16][64];
    __shared__ float Sl[16][64];
    __shared__ float Cs[16][64];
    __shared__ float Ms[16][64];
    const int b = blockIdx.x;
    const int tid = threadIdx.x;
    const int n = tid & 63, c = tid >> 6;
    const int t0 = b * Ss + c * 64;
    const float Aval = -expf(A_log_l[n]);

    {
        const float* pp = part + (size_t)(t0 + n) * 8;
        float ps = 0.f;
#pragma unroll
        for (int j = 0; j < 8; ++j) ps += pp[j];
        Ms[c][n] = ps * (1.f / 1024.f);
    }
    __syncthreads();

    float S = 0.f, msum = 0.f;
#pragma unroll 8
    for (int t = 0; t < 64; ++t) {
        const float mt = Ms[c][t];
        msum += mt;
        S = fmaf(expf(Aval * mt), S, u[(size_t)(t0 + t) * 128 + n]);
    }
    Ps[c][n] = expf(Aval * msum);
    Sl[c][n] = S;
    __syncthreads();

    if (c == 0) {
        float carry = 0.f;
#pragma unroll
        for (int cc = 0; cc < 16; ++cc) {
            Cs[cc][n] = carry;
            carry = fmaf(Ps[cc][n], carry, Sl[cc][n]);
        }
    }
    __syncthreads();

    float st = Cs[c][n];
#pragma unroll 4
    for (int t = 0; t < 64; ++t) {
        st = fmaf(expf(Aval * Ms[c][t]), st, u[(size_t)(t0 + t) * 128 + n]);
        float r = st;
#pragma unroll
        for (int off = 32; off; off >>= 1) r += __shfl_xor(r, off);
        if (n == 0) ssum[t0 + t] = r;
    }
}

__global__ __launch_bounds__(256) void y_gate_kernel(
    ushort_t* __restrict__ xi, const ushort_t* __restrict__ res,
    const float* __restrict__ ssum)
{
    const size_t i8 = (size_t)blockIdx.x * blockDim.x + threadIdx.x;
    const int t = (int)(i8 >> 8);
    const float sv = ssum[t];
    uint4 xw = *(const uint4*)&xi[i8 * 8];
    const uint4 rw = *(const uint4*)&res[i8 * 8];
    const uint_t xs[4] = {xw.x, xw.y, xw.z, xw.w};
    const uint_t rs[4] = {rw.x, rw.y, rw.z, rw.w};
    uint_t os[4];
#pragma unroll
    for (int j = 0; j < 4; ++j) {
        const float x0 = bf2f(xs[j] & 0xffffu), x1 = bf2f(xs[j] >> 16);
        const float r0 = bf2f(rs[j] & 0xffffu), r1 = bf2f(rs[j] >> 16);
        os[j] = (uint_t)f2bf(sv * x0 * siluf(r0)) | ((uint_t)f2bf(sv * x1 * siluf(r1)) << 16);
    }
    *(uint4*)&xi[i8 * 8] = make_uint4(os[0], os[1], os[2], os[3]);
}

// ---------------------------------------------------------------
// MFMA flash attention (round 16: dbuf K/V + setprio).
// ---------------------------------------------------------------
__global__ __launch_bounds__(256) void attn_mfma_kernel(
    const ushort_t* __restrict__ qkv, const ushort_t* __restrict__ vt,
    ushort_t* __restrict__ out)
{
    __shared__ ushort_t Ks[2][64 * 64];
    __shared__ ushort_t Vs[2][64 * 64];
    __shared__ __attribute__((aligned(16))) ushort_t Pb[4][2560];

    const int tid = threadIdx.x;
    const int lane = tid & 63, wid = tid >> 6;
    const int b = blockIdx.z, h = blockIdx.y;
    const int q0 = blockIdx.x * 128 + wid * 32;
    const int l15 = lane & 15, lg = lane >> 4;
    constexpr float CEXP = 0.125f * 1.44269504f;

    short8 qf[2][2];
#pragma unroll
    for (int mi = 0; mi < 2; ++mi)
#pragma unroll
        for (int kk = 0; kk < 2; ++kk)
            qf[mi][kk] = *(const short8*)&qkv[(size_t)(b * Ss + q0 + mi * 16 + l15) * 3072
                                              + h * 64 + kk * 32 + lg * 8];

    f32x4 oacc[2][4];
#pragma unroll
    for (int mi = 0; mi < 2; ++mi)
#pragma unroll
        for (int nj = 0; nj < 4; ++nj) { oacc[mi][nj][0]=0.f; oacc[mi][nj][1]=0.f; oacc[mi][nj][2]=0.f; oacc[mi][nj][3]=0.f; }
    float lrun[2][4];
#pragma unroll
    for (int mi = 0; mi < 2; ++mi)
#pragma unroll
        for (int r = 0; r < 4; ++r) lrun[mi][r] = 0.f;

    const int srow = lane >> 3;
    const int scc  = (lane & 7) ^ srow;
    const ushort_t* Kg = qkv + (size_t)(b * Ss + wid * 16 + srow) * 3072 + 1024 + h * 64 + scc * 8;
    const ushort_t* Vg = vt + (size_t)((b * Hh + h) * 64 + wid * 16 + srow) * Ss + scc * 8;

    auto STAGE_KV = [&](int buf, int kt) {
#pragma unroll
        for (int j = 0; j < 2; ++j) {
            gload_lds16(Kg + (size_t)(kt * 64 + j * 8) * 3072, Ks[buf] + (wid * 16 + j * 8) * 64);
            gload_lds16(Vg + (size_t)j * 8 * Ss + kt * 64,     Vs[buf] + (wid * 16 + j * 8) * 64);
        }
    };

    constexpr int NT = Ss / 64;
    STAGE_KV(0, 0);
    int cur = 0;
    for (int kt = 0; kt < NT; ++kt) {
        if (kt + 1 < NT) STAGE_KV(cur ^ 1, kt + 1);
        wait_vm((kt + 1 < NT) ? 4 : 0);
        __builtin_amdgcn_s_barrier();

        f32x4 sacc[2][4];
#pragma unroll
        for (int mi = 0; mi < 2; ++mi)
#pragma unroll
            for (int nj = 0; nj < 4; ++nj) { sacc[mi][nj][0]=0.f; sacc[mi][nj][1]=0.f; sacc[mi][nj][2]=0.f; sacc[mi][nj][3]=0.f; }
        __builtin_amdgcn_s_setprio(1);
#pragma unroll
        for (int kk = 0; kk < 2; ++kk) {
            short8 kf[4];
#pragma unroll
            for (int nj = 0; nj < 4; ++nj) {
                const int row = nj * 16 + l15;
                const int ch = (kk * 4 + lg) ^ (row & 7);
                kf[nj] = *(const short8*)&Ks[cur][row * 64 + ch * 8];
            }
#pragma unroll
            for (int mi = 0; mi < 2; ++mi)
#pragma unroll
                for (int nj = 0; nj < 4; ++nj)
                    sacc[mi][nj] = __builtin_amdgcn_mfma_f32_16x16x32_bf16(
                        qf[mi][kk], kf[nj], sacc[mi][nj], 0, 0, 0);
        }
        __builtin_amdgcn_s_setprio(0);

#pragma unroll
        for (int mi = 0; mi < 2; ++mi)
#pragma unroll
            for (int nj = 0; nj < 4; ++nj) {
                const int bi = mi * 2 + (nj >> 1);
                const int chsw = ((nj & 1) * 2 + (l15 >> 3)) ^ lg;
#pragma unroll
                for (int r = 0; r < 4; ++r) {
                    const float p = exp2f(sacc[mi][nj][r] * CEXP);
                    lrun[mi][r] += p;
                    const int q15 = lg * 4 + r;
                    Pb[wid][bi * 640 + q15 * 40 + chsw * 8 + (lane & 7)] = f2bf(p);
                }
            }

        __builtin_amdgcn_s_setprio(1);
#pragma unroll
        for (int kk = 0; kk < 2; ++kk) {
            short8 pa[2], vb[4];
#pragma unroll
            for (int mi = 0; mi < 2; ++mi) {
                const int chsw = lg ^ (l15 >> 2);
                pa[mi] = *(const short8*)&Pb[wid][(mi * 2 + kk) * 640 + l15 * 40 + chsw * 8];
            }
#pragma unroll
            for (int nj = 0; nj < 4; ++nj) {
                const int row = nj * 16 + l15;
                const int ch = (kk * 4 + lg) ^ (row & 7);
                vb[nj] = *(const short8*)&Vs[cur][row * 64 + ch * 8];
            }
#pragma unroll
            for (int mi = 0; mi < 2; ++mi)
#pragma unroll
                for (int nj = 0; nj < 4; ++nj)
                    oacc[mi][nj] = __builtin_amdgcn_mfma_f32_16x16x32_bf16(
                        pa[mi], vb[nj], oacc[mi][nj], 0, 0, 0);
        }
        __builtin_amdgcn_s_setprio(0);

        asm volatile("s_waitcnt lgkmcnt(0)" ::: "memory");
        __builtin_amdgcn_s_barrier();
        cur ^= 1;
    }

#pragma unroll
    for (int mi = 0; mi < 2; ++mi)
#pragma unroll
        for (int r = 0; r < 4; ++r) {
            float s = lrun[mi][r];
#pragma unroll
            for (int off = 1; off < 16; off <<= 1) s += __shfl_xor(s, off);
            lrun[mi][r] = 1.f / s;
        }
#pragma unroll
    for (int mi = 0; mi < 2; ++mi)
#pragma unroll
        for (int r = 0; r < 4; ++r) {
            const int q = q0 + mi * 16 + lg * 4 + r;
            const float inv = lrun[mi][r];
#pragma unroll
            for (int nj = 0; nj < 4; ++nj)
                out[(size_t)(b * Ss + q) * Dd + h * 64 + nj * 16 + l15] =
                    f2bf(oacc[mi][nj][r] * inv);
        }
}

// ---------------------------------------------------------------
extern "C" void kernel_launch(void* const* d_in, const int* in_sizes, int n_in,
                              void* d_out, int out_size, void* d_ws, size_t ws_size,
                              hipStream_t stream)
{
    const float* x_in  = (const float*)d_in[0];
    const float* A_log = (const float*)d_in[1];
    const float* Dp    = (const float*)d_in[2];
    const float* W_in  = (const float*)d_in[3];
    const float* b_in  = (const float*)d_in[4];
    const float* W_xp  = (const float*)d_in[5];
    const float* b_xp  = (const float*)d_in[6];
    const float* W_dt  = (const float*)d_in[7];
    const float* b_dt  = (const float*)d_in[8];
    const float* W_out = (const float*)d_in[9];
    const float* b_out = (const float*)d_in[10];
    const float* W_qkv = (const float*)d_in[11];
    const float* b_qkv = (const float*)d_in[12];
    const float* W_ao  = (const float*)d_in[13];
    const float* b_ao  = (const float*)d_in[14];
    const float* g1    = (const float*)d_in[15];
    const float* be1   = (const float*)d_in[16];
    const float* g2    = (const float*)d_in[17];
    const float* be2   = (const float*)d_in[18];
    const float* W_f1  = (const float*)d_in[19];
    const float* b_f1  = (const float*)d_in[20];
    const float* W_f2  = (const float*)d_in[21];
    const float* b_f2  = (const float*)d_in[22];

    // ---- workspace layout ----
    float* xf      = (float*)d_ws;                  // 4M f32 residual stream
    float* a3      = xf + 4194304;                  // 4M f32 mo/po
    float* ub      = a3 + 4194304;                  // 4096*128 f32 (padded u)
    float* sb      = ub + 524288;                   // 4096
    float* part    = sb + 4096;                     // 4096*8 delta row partials
    float* bcat    = part + 32768;                  // 1152
    ushort_t* xb    = (ushort_t*)(bcat + 1152);     // 4M bf16
    ushort_t* xi_b  = xb + 4194304;                 // 8M bf16 (xi -> y)
    ushort_t* res_b = xi_b + 8388608;               // 8M bf16
    ushort_t* qh_b  = res_b + 8388608;              // 16M bf16 (qkv / ffn hidden)
    ushort_t* ao_b  = qh_b + 16777216;              // 4M bf16
    ushort_t* Wb    = ao_b + 4194304;               // 21.23M bf16 weights
    ushort_t* vt_b  = Wb + W_TOTAL;                 // 4M bf16 (V transposed)

    hipMemcpyAsync(xf, x_in, (size_t)TOKENS * Dd * sizeof(float),
                   hipMemcpyDeviceToDevice, stream);
    cvt_f32_bf16_kernel<<<dim3(4096), dim3(256), 0, stream>>>(x_in, xb);

    const dim3 blk(256), blk512(512);

    for (int l = 0; l < 4; ++l) {
        convert_weights_kernel<<<dim3(2048), blk, 0, stream>>>(
            W_in + (size_t)l * 4194304, W_dt + (size_t)l * 2097152,
            W_xp + (size_t)l * 131072,  W_out + (size_t)l * 2097152,
            W_qkv + (size_t)l * 3145728, W_ao + (size_t)l * 1048576,
            W_f1 + (size_t)l * 4194304, W_f2 + (size_t)l * 4194304,
            b_dt + (size_t)l * 1024, b_xp + (size_t)l * Nn, Wb, bcat);

        // 1) xr = x @ W_in^T: silu half -> xi_b, raw half -> res_b (256^2, BK=64)
        gemm_wide256<EPI_SPLIT><<<dim3(16, 16), blk512, 0, stream>>>(
            xb, Wb + O_IN, b_in + (size_t)l * 4096, TOKENS, 4096, 1024,
            xi_b, res_b);
        // 2+3+4) fused: [delta|u]; delta -> row partials (part), u -> ub
        gemm_narrow64<EPI_DTXP, 8><<<dim3(9, 64), blk, 0, stream>>>(
            xi_b, Wb + O_DT, bcat, TOKENS, 1152, 2048,
            part, ub, nullptr, nullptr, nullptr);
        // 5) fused chunked scan -> sb
        scan_fused_kernel<<<dim3(Bb), dim3(1024), 0, stream>>>(
            A_log + (size_t)l * Nn, part, ub, sb);
        // 6) y = ssum * xi * silu(res) (in place, bf16)
        y_gate_kernel<<<dim3(4096), blk, 0, stream>>>(xi_b, res_b, sb);
        // 7) mamba_out = y @ W_out^T + x*Dp -> a3 (fp32)
        gemm_narrow64<EPI_DP, 8><<<dim3(8, 64), blk, 0, stream>>>(
            xi_b, Wb + O_OUT, b_out + (size_t)l * 1024, TOKENS, 1024, 2048,
            a3, nullptr, nullptr, xf, Dp + (size_t)l * 1024);
        // 8) x = LN(x + mamba_out)
        ln_residual_kernel<<<dim3(TOKENS), blk, 0, stream>>>(
            xf, a3, g1 + (size_t)l * 1024, be1 + (size_t)l * 1024, xb);
        // 9) qkv = x @ W_qkv^T; K/Q -> qh_b, V transposed -> vt_b (128^2)
        gemm_mfma<EPI_QKV, 3, 4><<<dim3(24, 32), blk, 0, stream>>>(
            xb, Wb + O_QKV, b_qkv + (size_t)l * 3072, TOKENS, 3072, 1024,
            qh_b, vt_b);
        // 10) MFMA flash attention (dbuf K/V) -> ao_b
        attn_mfma_kernel<<<dim3(8, Hh, Bb), blk, 0, stream>>>(qh_b, vt_b, ao_b);
        // 11) proj = attn @ W_ao^T -> a3 (fp32)
        gemm_narrow64<EPI_F32, 8><<<dim3(8, 64), blk, 0, stream>>>(
            ao_b, Wb + O_AO, b_ao + (size_t)l * 1024, TOKENS, 1024, 1024,
            a3, nullptr, nullptr, nullptr, nullptr);
        // 12) x = LN(x + proj)
        ln_residual_kernel<<<dim3(TOKENS), blk, 0, stream>>>(
            xf, a3, g2 + (size_t)l * 1024, be2 + (size_t)l * 1024, xb);
        // 13) h = gelu(x @ W_f1^T) -> qh_b (256^2, BK=64)
        gemm_wide256<EPI_GELU><<<dim3(16, 16), blk512, 0, stream>>>(
            xb, Wb + O_F1, b_f1 + (size_t)l * 4096, TOKENS, 4096, 1024,
            qh_b, nullptr);
        // 14) x = x + h @ W_f2^T (fp32 in place) and xb (bf16)
        gemm_narrow64<EPI_RESID, 8><<<dim3(8, 64), blk, 0, stream>>>(
            qh_b, Wb + O_F2, b_f2 + (size_t)l * 1024, TOKENS, 1024, 4096,
            xf, nullptr, xb, xf, nullptr);
    }

    hipMemcpyAsync(d_out, xf, (size_t)TOKENS * Dd * sizeof(float),
                   hipMemcpyDeviceToDevice, stream);
    (void)in_sizes; (void)n_in; (void)out_size; (void)ws_size;
}